// Round 10
// baseline (490.667 us; speedup 1.0000x reference)
//
#include <hip/hip_runtime.h>

typedef unsigned short ushort_t;
typedef __attribute__((ext_vector_type(8))) short bf16x8;
typedef __attribute__((ext_vector_type(4))) float f32x4;

#define B_SZ   16
#define NQ     4096
#define NKV    77
#define NKVP   80
#define QDIM   320
#define CDIM   768
#define HEADS  8
#define DHEAD  64
#define INNER  512
#define M_ROWS (B_SZ * NQ)

__device__ __forceinline__ ushort_t f2bf(float f) {
  unsigned u = __builtin_bit_cast(unsigned, f);
  u = (u + 0x7fffu + ((u >> 16) & 1u)) >> 16;
  return (ushort_t)u;
}

__device__ __forceinline__ void async16(const ushort_t* g, ushort_t* l) {
  __builtin_amdgcn_global_load_lds(
      (const __attribute__((address_space(1))) unsigned int*)g,
      (__attribute__((address_space(3))) unsigned int*)l,
      16, 0, 0);
}

__device__ __forceinline__ bf16x8 cvt8(f32x4 lo, f32x4 hi) {
  unsigned w0, w1, w2, w3;
  asm("v_cvt_pk_bf16_f32 %0, %1, %2" : "=v"(w0) : "v"(lo[0]), "v"(lo[1]));
  asm("v_cvt_pk_bf16_f32 %0, %1, %2" : "=v"(w1) : "v"(lo[2]), "v"(lo[3]));
  asm("v_cvt_pk_bf16_f32 %0, %1, %2" : "=v"(w2) : "v"(hi[0]), "v"(hi[1]));
  asm("v_cvt_pk_bf16_f32 %0, %1, %2" : "=v"(w3) : "v"(hi[2]), "v"(hi[3]));
  union { unsigned u[4]; bf16x8 v; } cv;
  cv.u[0] = w0; cv.u[1] = w1; cv.u[2] = w2; cv.u[3] = w3;
  return cv.v;
}

// ---------------- mask dtype detect + bias table ----------------
__global__ void mask_bias_kernel(const unsigned char* __restrict__ mraw,
                                 float* __restrict__ biasT) {
  __shared__ int s_u8, s_w4;
  if (threadIdx.x == 0) { s_u8 = 0; s_w4 = 0; }
  __syncthreads();
  const int nbytes = B_SZ * NKV;
  for (int i = threadIdx.x; i < nbytes; i += blockDim.x) {
    unsigned char v = mraw[i];
    if (v && (i & 3)) atomicOr(&s_u8, 1);
    if (v && ((i & 7) == 4)) atomicOr(&s_w4, 1);
  }
  __syncthreads();
  int mode = s_u8 ? 0 : (s_w4 ? 1 : 2);
  for (int i = threadIdx.x; i < B_SZ * NKVP; i += blockDim.x) {
    int b = i / NKVP, kv = i - b * NKVP;
    float bias = -2e30f;
    if (kv < NKV) {
      int idx = b * NKV + kv;
      long long m;
      if (mode == 0)      m = (long long)mraw[idx];
      else if (mode == 1) m = (long long)((const int*)mraw)[idx];
      else                m = ((const long long*)mraw)[idx];
      bias = m ? 0.0f : -1e30f;
    }
    biasT[i] = bias;
  }
}

// ---------------- casts ----------------
__global__ void cast_f32_bf16(const float* __restrict__ in,
                              ushort_t* __restrict__ out, int n4) {
  int i = blockIdx.x * blockDim.x + threadIdx.x;
  int stride = gridDim.x * blockDim.x;
  const float4* in4 = (const float4*)in;
  ushort4* out4 = (ushort4*)out;
  for (; i < n4; i += stride) {
    float4 v = in4[i];
    ushort4 o;
    o.x = f2bf(v.x); o.y = f2bf(v.y); o.z = f2bf(v.z); o.w = f2bf(v.w);
    out4[i] = o;
  }
}

__global__ void tcast_f32_bf16(const float* __restrict__ in,
                               ushort_t* __restrict__ out,
                               int K, int N, int Npad, float scale) {
  int i = blockIdx.x * blockDim.x + threadIdx.x;
  int stride = gridDim.x * blockDim.x;
  int total = Npad * K;
  for (; i < total; i += stride) {
    int n = i / K, k = i - n * K;
    out[i] = (n < N) ? f2bf(in[(size_t)k * N + n] * scale) : (ushort_t)0;
  }
}

// ---------------- generic 128x128 GEMM (kv projection only) ----------
__global__ __launch_bounds__(256) void gemm_bf16(
    const ushort_t* __restrict__ A, const ushort_t* __restrict__ Bt,
    ushort_t* __restrict__ Cb,
    int K, int Astride, int Bstride, int Cstride) {
  __shared__ ushort_t As[128 * 64];
  __shared__ ushort_t Bs[128 * 64];
  const int tid = threadIdx.x;
  const int wid = tid >> 6, lane = tid & 63;
  const int wr = wid >> 1, wc = wid & 1;
  const int tileM = blockIdx.x * 128, tileN = blockIdx.y * 128;

  f32x4 acc[4][4];
#pragma unroll
  for (int m = 0; m < 4; ++m)
#pragma unroll
    for (int n = 0; n < 4; ++n) acc[m][n] = (f32x4){0.f, 0.f, 0.f, 0.f};

  const int srow = lane >> 3;
  const int scol = (lane & 7) * 8;

  for (int kt = 0; kt < K; kt += 64) {
    __syncthreads();
#pragma unroll
    for (int j = 0; j < 4; ++j) {
      int s = wid * 4 + j;
      const ushort_t* ga = A + (size_t)(tileM + s * 8 + srow) * Astride + kt + scol;
      const ushort_t* gb = Bt + (size_t)(tileN + s * 8 + srow) * Bstride + kt + scol;
      async16(ga, As + s * 512);
      async16(gb, Bs + s * 512);
    }
    __syncthreads();
#pragma unroll
    for (int kc = 0; kc < 2; ++kc) {
      bf16x8 af[4], bfr[4];
#pragma unroll
      for (int m = 0; m < 4; ++m)
        af[m] = *(const bf16x8*)&As[(wr * 64 + m * 16 + (lane & 15)) * 64 + kc * 32 + (lane >> 4) * 8];
#pragma unroll
      for (int n = 0; n < 4; ++n)
        bfr[n] = *(const bf16x8*)&Bs[(wc * 64 + n * 16 + (lane & 15)) * 64 + kc * 32 + (lane >> 4) * 8];
#pragma unroll
      for (int m = 0; m < 4; ++m)
#pragma unroll
        for (int n = 0; n < 4; ++n)
          acc[m][n] = __builtin_amdgcn_mfma_f32_16x16x32_bf16(af[m], bfr[n], acc[m][n], 0, 0, 0);
    }
  }

  const int r0 = tileM + wr * 64;
  const int c0 = tileN + wc * 64;
  const int rl2 = (lane >> 4) * 4;
  const int cl = lane & 15;
#pragma unroll
  for (int m = 0; m < 4; ++m)
#pragma unroll
    for (int n = 0; n < 4; ++n) {
      int col = c0 + n * 16 + cl;
#pragma unroll
      for (int r = 0; r < 4; ++r)
        Cb[(size_t)(r0 + m * 16 + rl2 + r) * Cstride + col] = f2bf(acc[m][n][r]);
    }
}

// ---------------- W2T[b][h*80+kv][320] = 0.125 * Wq_h^T-combined with K ----
// W2T[kv,p] = 0.125 * sum_d Wq[p, h*64+d] * K[b,kv,h,d];  kv>=77 -> 0
__global__ __launch_bounds__(512) void w2t_kernel(
    const float* __restrict__ Wq, const ushort_t* __restrict__ kvb,
    ushort_t* __restrict__ W2T) {
  const int b = blockIdx.x;
  const int tid = threadIdx.x, h = tid >> 6, lane = tid & 63;
  const int rl = lane & 15, g = lane >> 4;

  bf16x8 af[5][2];  // A[kv = m*16+rl][d = kc*32+g*8]  (K rows; pad rows garbage, predicated)
#pragma unroll
  for (int m = 0; m < 5; ++m)
#pragma unroll
    for (int kc = 0; kc < 2; ++kc)
      af[m][kc] = *(const bf16x8*)&kvb[(size_t)(b * NKV + m * 16 + rl) * 1024 + h * 64 + kc * 32 + g * 8];

  const float4* Wq4 = (const float4*)Wq;
  for (int n = 0; n < 20; ++n) {
    bf16x8 bfr[2];
#pragma unroll
    for (int kc = 0; kc < 2; ++kc) {
      size_t idx = (size_t)(n * 16 + rl) * 128 + h * 16 + kc * 8 + g * 2;
      f32x4 lo = *(const f32x4*)&Wq4[idx];
      f32x4 hi = *(const f32x4*)&Wq4[idx + 1];
      lo *= 0.125f; hi *= 0.125f;
      bfr[kc] = cvt8(lo, hi);
    }
    f32x4 acc[5];
#pragma unroll
    for (int m = 0; m < 5; ++m) acc[m] = (f32x4){0.f, 0.f, 0.f, 0.f};
#pragma unroll
    for (int m = 0; m < 5; ++m)
#pragma unroll
      for (int kc = 0; kc < 2; ++kc)
        acc[m] = __builtin_amdgcn_mfma_f32_16x16x32_bf16(af[m][kc], bfr[kc], acc[m], 0, 0, 0);
#pragma unroll
    for (int m = 0; m < 5; ++m)
#pragma unroll
      for (int r = 0; r < 4; ++r) {
        int kv = m * 16 + g * 4 + r;
        ushort_t v = (kv < NKV) ? f2bf(acc[m][r]) : (ushort_t)0;
        W2T[((size_t)b * 640 + h * NKVP + kv) * QDIM + n * 16 + rl] = v;
      }
  }
}

// ---------------- W3T[b][p][h*80+kv] = sum_d V[b,kv,h,d] * Wo[h*64+d, p] ---
// (Wo^T = Wob[p][inner]); kv>=77 contributes 0 via zeroed B-frags.
__global__ __launch_bounds__(512) void w3t_kernel(
    const ushort_t* __restrict__ Wob, const ushort_t* __restrict__ kvb,
    ushort_t* __restrict__ W3T) {
  const int b = blockIdx.x;
  const int tid = threadIdx.x, h = tid >> 6, lane = tid & 63;
  const int rl = lane & 15, g = lane >> 4;

  bf16x8 bfr[5][2];  // B[kv = n*16+rl][d]
#pragma unroll
  for (int n = 0; n < 5; ++n) {
    int kv = n * 16 + rl;
#pragma unroll
    for (int kc = 0; kc < 2; ++kc) {
      bfr[n][kc] = (bf16x8){0, 0, 0, 0, 0, 0, 0, 0};
      if (kv < NKV)
        bfr[n][kc] = *(const bf16x8*)&kvb[(size_t)(b * NKV + kv) * 1024 + 512 + h * 64 + kc * 32 + g * 8];
    }
  }
  for (int m = 0; m < 20; ++m) {
    bf16x8 af[2];  // A[p = m*16+rl][d]
#pragma unroll
    for (int kc = 0; kc < 2; ++kc)
      af[kc] = *(const bf16x8*)&Wob[(size_t)(m * 16 + rl) * INNER + h * 64 + kc * 32 + g * 8];
    f32x4 acc[5];
#pragma unroll
    for (int n = 0; n < 5; ++n) acc[n] = (f32x4){0.f, 0.f, 0.f, 0.f};
#pragma unroll
    for (int n = 0; n < 5; ++n)
#pragma unroll
      for (int kc = 0; kc < 2; ++kc)
        acc[n] = __builtin_amdgcn_mfma_f32_16x16x32_bf16(af[kc], bfr[n][kc], acc[n], 0, 0, 0);
#pragma unroll
    for (int n = 0; n < 5; ++n)
#pragma unroll
      for (int r = 0; r < 4; ++r)
        W3T[((size_t)b * QDIM + m * 16 + g * 4 + r) * 640 + h * NKVP + n * 16 + rl] = f2bf(acc[n][r]);
  }
}

// ======================= MEGA: s = x@W2, softmax, out = P@W3 + bo ==========
// Block = (64 q-rows, b via XCD swizzle). 512 thr, 8 waves, 64 KB LDS,
// 2 blocks/CU. 4 passes x {A: wave-head s(16rowsx80kv) + softmax;
// P->LDS quarter; B: all waves out += P @ W3T[pass k-range]}.
__global__ __launch_bounds__(512, 4) void mega_attn(
    const float* __restrict__ x, const ushort_t* __restrict__ W2T,
    const ushort_t* __restrict__ W3T, const float* __restrict__ biasT,
    const float* __restrict__ bo, float* __restrict__ out) {
  __shared__ ushort_t xs[64 * 320];   // 40960 B, 16B-granule XOR swizzle
  __shared__ ushort_t Pq[64 * 192];   // 24576 B, rows 384 B (24 granules)
  const int wgid = blockIdx.x;
  const int swz = (wgid & 7) * 128 + (wgid >> 3);   // same-b contiguous per XCD
  const int b = swz >> 6, qt = swz & 63;
  const int tid = threadIdx.x, wid = tid >> 6, lane = tid & 63;
  const int rl = lane & 15, g = lane >> 4;
  const size_t Mbase = (size_t)b * NQ + qt * 64;

  // stage x -> bf16 LDS (read once from HBM)
#pragma unroll
  for (int i = 0; i < 5; ++i) {
    int c = tid + i * 512;
    int row = c / 40, c16 = c - row * 40;
    const f32x4* src = (const f32x4*)&x[(Mbase + row) * QDIM + c16 * 8];
    *(bf16x8*)&xs[row * 320 + ((c16 ^ (row & 7)) << 3)] = cvt8(src[0], src[1]);
  }

  const int wr2 = wid & 1, wc2 = wid >> 1;   // phase-B tile: rows 32, cols 80
  float bias_v[5], bo_v[5];
#pragma unroll
  for (int n = 0; n < 5; ++n) {
    bias_v[n] = biasT[b * NKVP + n * 16 + rl];
    bo_v[n] = bo[wc2 * 80 + n * 16 + rl];
  }

  f32x4 acc_o[2][5];
#pragma unroll
  for (int m = 0; m < 2; ++m)
#pragma unroll
    for (int n = 0; n < 5; ++n) acc_o[m][n] = (f32x4){0.f, 0.f, 0.f, 0.f};

  const int arow = (wid & 3) * 16;   // phase-A rows for this wave
  const int hl = wid >> 2;           // head-local within pass (0/1)
  const int kc0a = wgid % 10, kc0b = wgid % 5;  // contention decorrelation

  __syncthreads();

#pragma unroll 1
  for (int pass = 0; pass < 4; ++pass) {
    const int h = pass * 2 + hl;

    // ---- phase A: s[16 rows][80 kv] = xs @ W2T_h ----
    f32x4 s[5];
#pragma unroll
    for (int n = 0; n < 5; ++n) s[n] = (f32x4){0.f, 0.f, 0.f, 0.f};
    const ushort_t* W2b = W2T + ((size_t)b * 640 + h * NKVP) * QDIM;
#pragma unroll
    for (int i = 0; i < 10; ++i) {
      int kc = kc0a + i; if (kc >= 10) kc -= 10;
      const int row = arow + rl;
      bf16x8 af = *(const bf16x8*)&xs[row * 320 + (((kc * 4 + g) ^ (row & 7)) << 3)];
#pragma unroll
      for (int n = 0; n < 5; ++n) {
        bf16x8 bfr = *(const bf16x8*)&W2b[(size_t)(n * 16 + rl) * QDIM + kc * 32 + g * 8];
        s[n] = __builtin_amdgcn_mfma_f32_16x16x32_bf16(af, bfr, s[n], 0, 0, 0);
      }
    }

    // ---- softmax over 80 kv (per row = g*4+r), normalized P ----
    float mx[4] = {-3.0e38f, -3.0e38f, -3.0e38f, -3.0e38f};
#pragma unroll
    for (int n = 0; n < 5; ++n)
#pragma unroll
      for (int r = 0; r < 4; ++r) {
        float v = s[n][r] + bias_v[n];
        s[n][r] = v;
        mx[r] = fmaxf(mx[r], v);
      }
#pragma unroll
    for (int d = 1; d < 16; d <<= 1)
#pragma unroll
      for (int r = 0; r < 4; ++r) mx[r] = fmaxf(mx[r], __shfl_xor(mx[r], d, 64));
    float sum[4] = {0.f, 0.f, 0.f, 0.f};
#pragma unroll
    for (int n = 0; n < 5; ++n)
#pragma unroll
      for (int r = 0; r < 4; ++r) {
        float p = __expf(s[n][r] - mx[r]);
        s[n][r] = p;
        sum[r] += p;
      }
#pragma unroll
    for (int d = 1; d < 16; d <<= 1)
#pragma unroll
      for (int r = 0; r < 4; ++r) sum[r] += __shfl_xor(sum[r], d, 64);
    float rcp[4];
#pragma unroll
    for (int r = 0; r < 4; ++r) rcp[r] = 1.0f / sum[r];

    __syncthreads();   // previous pass-B readers done with Pq
#pragma unroll
    for (int n = 0; n < 5; ++n)
#pragma unroll
      for (int r = 0; r < 4; ++r) {
        int row = arow + g * 4 + r;
        int g16 = hl * 10 + n * 2 + (rl >> 3);
        Pq[row * 192 + (((g16) ^ (row & 7)) << 3) + (rl & 7)] = f2bf(s[n][r] * rcp[r]);
      }
    __syncthreads();   // Pq ready

    // ---- phase B: acc_o += Pq[64][160] @ W3T[pass k-range] ----
    const ushort_t* W3b = W3T + (size_t)b * QDIM * 640 + pass * 160;
#pragma unroll
    for (int i = 0; i < 5; ++i) {
      int kc = kc0b + i; if (kc >= 5) kc -= 5;
      bf16x8 paf[2];
#pragma unroll
      for (int m = 0; m < 2; ++m) {
        const int row = wr2 * 32 + m * 16 + rl;
        paf[m] = *(const bf16x8*)&Pq[row * 192 + (((kc * 4 + g) ^ (row & 7)) << 3)];
      }
#pragma unroll
      for (int n = 0; n < 5; ++n) {
        bf16x8 bfr = *(const bf16x8*)&W3b[(size_t)(wc2 * 80 + n * 16 + rl) * 640 + kc * 32 + g * 8];
#pragma unroll
        for (int m = 0; m < 2; ++m)
          acc_o[m][n] = __builtin_amdgcn_mfma_f32_16x16x32_bf16(paf[m], bfr, acc_o[m][n], 0, 0, 0);
      }
    }
  }

  // ---- epilogue: f32 out + bias (320 cols exact, no predicate) ----
#pragma unroll
  for (int n = 0; n < 5; ++n)
#pragma unroll
    for (int m = 0; m < 2; ++m)
#pragma unroll
      for (int r = 0; r < 4; ++r)
        out[(Mbase + wr2 * 32 + m * 16 + g * 4 + r) * QDIM + wc2 * 80 + n * 16 + rl] =
            acc_o[m][n][r] + bo_v[n];
}

// ---------------- host ----------------
extern "C" void kernel_launch(void* const* d_in, const int* in_sizes, int n_in,
                              void* d_out, int out_size, void* d_ws, size_t ws_size,
                              hipStream_t stream) {
  (void)in_sizes; (void)n_in; (void)out_size; (void)ws_size;
  const float* x   = (const float*)d_in[0];
  const float* ctx = (const float*)d_in[1];
  const unsigned char* mask = (const unsigned char*)d_in[2];
  const float* Wq = (const float*)d_in[3];
  const float* Wk = (const float*)d_in[4];
  const float* Wv = (const float*)d_in[5];
  const float* Wo = (const float*)d_in[6];
  const float* bo = (const float*)d_in[7];
  float* out = (float*)d_out;

  char* ws = (char*)d_ws;
  size_t off = 0;
  auto alloc = [&](size_t bytes) {
    char* p = ws + off;
    off += (bytes + 255) & ~(size_t)255;
    return p;
  };
  float*    biasT = (float*)alloc(B_SZ * NKVP * sizeof(float));
  ushort_t* cb    = (ushort_t*)alloc((size_t)1280 * CDIM * 2);
  ushort_t* Wkvb  = (ushort_t*)alloc((size_t)1024 * CDIM * 2);
  ushort_t* Wob   = (ushort_t*)alloc((size_t)384 * INNER * 2);
  ushort_t* kvb   = (ushort_t*)alloc((size_t)1280 * 1024 * 2);
  ushort_t* W2T   = (ushort_t*)alloc((size_t)B_SZ * 640 * QDIM * 2);  // [b][h*80+kv][320]
  ushort_t* W3T   = (ushort_t*)alloc((size_t)B_SZ * QDIM * 640 * 2);  // [b][p][h*80+kv]

  mask_bias_kernel<<<1, 256, 0, stream>>>(mask, biasT);
  cast_f32_bf16<<<512, 256, 0, stream>>>(ctx, cb, B_SZ * NKV * CDIM / 4);
  tcast_f32_bf16<<<1536, 256, 0, stream>>>(Wk, Wkvb, CDIM, INNER, INNER, 1.0f);
  tcast_f32_bf16<<<1536, 256, 0, stream>>>(Wv, Wkvb + (size_t)INNER * CDIM, CDIM, INNER, INNER, 1.0f);
  tcast_f32_bf16<<<768, 256, 0, stream>>>(Wo, Wob, INNER, QDIM, 384, 1.0f);

  // [k|v] = ctx @ [Wk|Wv]
  dim3 g2(1280 / 128, 1024 / 128);
  gemm_bf16<<<g2, 256, 0, stream>>>(cb, Wkvb, kvb, CDIM, CDIM, CDIM, 1024);
  // per-(b,h) folded weight panels
  w2t_kernel<<<B_SZ, 512, 0, stream>>>(Wq, kvb, W2T);
  w3t_kernel<<<B_SZ, 512, 0, stream>>>(Wob, kvb, W3T);
  // fused everything else: x read once, out written once
  mega_attn<<<M_ROWS / 64, 512, 0, stream>>>(x, W2T, W3T, biasT, bo, out);
}

// Round 11
// 182.749 us; speedup vs baseline: 2.6849x; 2.6849x over previous
//
#include <hip/hip_runtime.h>

typedef unsigned short ushort_t;
typedef __attribute__((ext_vector_type(8))) short bf16x8;
typedef __attribute__((ext_vector_type(4))) float f32x4;

#define B_SZ   16
#define NQ     4096
#define NKV    77
#define QDIM   320
#define CDIM   768
#define HEADS  8
#define DHEAD  64
#define INNER  512
#define M_ROWS (B_SZ * NQ)   // 65536
#define VT_STR 104

__device__ __forceinline__ ushort_t f2bf(float f) {
  unsigned u = __builtin_bit_cast(unsigned, f);
  u = (u + 0x7fffu + ((u >> 16) & 1u)) >> 16;
  return (ushort_t)u;
}

__device__ __forceinline__ void async16(const ushort_t* g, ushort_t* l) {
  __builtin_amdgcn_global_load_lds(
      (const __attribute__((address_space(1))) unsigned int*)g,
      (__attribute__((address_space(3))) unsigned int*)l,
      16, 0, 0);
}

__device__ __forceinline__ bf16x8 cvt8(f32x4 lo, f32x4 hi) {
  unsigned w0, w1, w2, w3;
  asm("v_cvt_pk_bf16_f32 %0, %1, %2" : "=v"(w0) : "v"(lo[0]), "v"(lo[1]));
  asm("v_cvt_pk_bf16_f32 %0, %1, %2" : "=v"(w1) : "v"(lo[2]), "v"(lo[3]));
  asm("v_cvt_pk_bf16_f32 %0, %1, %2" : "=v"(w2) : "v"(hi[0]), "v"(hi[1]));
  asm("v_cvt_pk_bf16_f32 %0, %1, %2" : "=v"(w3) : "v"(hi[2]), "v"(hi[3]));
  union { unsigned u[4]; bf16x8 v; } cv;
  cv.u[0] = w0; cv.u[1] = w1; cv.u[2] = w2; cv.u[3] = w3;
  return cv.v;
}

// counted waitcnt: loads stay in flight across barriers (T3/T4)
#define VMCNT(N) asm volatile("s_waitcnt vmcnt(" #N ")" ::: "memory")

// ---------------- mask dtype detect + bias table ----------------
__global__ void mask_bias_kernel(const unsigned char* __restrict__ mraw,
                                 float* __restrict__ biasT) {
  __shared__ int s_u8, s_w4;
  if (threadIdx.x == 0) { s_u8 = 0; s_w4 = 0; }
  __syncthreads();
  const int nbytes = B_SZ * NKV;
  for (int i = threadIdx.x; i < nbytes; i += blockDim.x) {
    unsigned char v = mraw[i];
    if (v && (i & 3)) atomicOr(&s_u8, 1);
    if (v && ((i & 7) == 4)) atomicOr(&s_w4, 1);
  }
  __syncthreads();
  int mode = s_u8 ? 0 : (s_w4 ? 1 : 2);
  for (int i = threadIdx.x; i < B_SZ * 80; i += blockDim.x) {
    int b = i / 80, kv = i - b * 80;
    float bias = -2e30f;
    if (kv < NKV) {
      int idx = b * NKV + kv;
      long long m;
      if (mode == 0)      m = (long long)mraw[idx];
      else if (mode == 1) m = (long long)((const int*)mraw)[idx];
      else                m = ((const long long*)mraw)[idx];
      bias = m ? 0.0f : -1e30f;
    }
    biasT[i] = bias;
  }
}

// ---------------- fused prep: ctx cast + all weight transpose-casts --------
// Flat index space:
//  [0, 236544)            ctx float4 cast -> cb
//  [236544, 400384)       Wqb[n][k] = bf16(0.125 * Wq[k][n])   (512 x 320)
//  [400384, 1186816)      Wkvb[n][k] = bf16(Wk|Wv [k][n])      (1024 x 768)
//  [1186816, 1383424)     Wob[n][k] = n<320 ? bf16(Wo[k][n]):0 (384 x 512)
#define PREP_T0 236544
#define PREP_T1 400384
#define PREP_T2 1186816
#define PREP_T3 1383424
__global__ void prep_kernel(const float* __restrict__ ctx, ushort_t* __restrict__ cb,
                            const float* __restrict__ Wq, ushort_t* __restrict__ Wqb,
                            const float* __restrict__ Wk, const float* __restrict__ Wv,
                            ushort_t* __restrict__ Wkvb,
                            const float* __restrict__ Wo, ushort_t* __restrict__ Wob) {
  int i = blockIdx.x * blockDim.x + threadIdx.x;
  const int stride = gridDim.x * blockDim.x;
  for (; i < PREP_T3; i += stride) {
    if (i < PREP_T0) {
      float4 v = ((const float4*)ctx)[i];
      ushort4 o;
      o.x = f2bf(v.x); o.y = f2bf(v.y); o.z = f2bf(v.z); o.w = f2bf(v.w);
      ((ushort4*)cb)[i] = o;
    } else if (i < PREP_T1) {
      int j = i - PREP_T0;
      int n = j / QDIM, k = j - n * QDIM;
      Wqb[j] = f2bf(Wq[(size_t)k * INNER + n] * 0.125f);
    } else if (i < PREP_T2) {
      int j = i - PREP_T1;
      int n = j / CDIM, k = j - n * CDIM;
      float v = (n < INNER) ? Wk[(size_t)k * INNER + n]
                            : Wv[(size_t)k * INNER + (n - INNER)];
      Wkvb[j] = f2bf(v);
    } else {
      int j = i - PREP_T2;
      int n = j / INNER, k = j - n * INNER;
      Wob[j] = (n < QDIM) ? f2bf(Wo[(size_t)k * QDIM + n]) : (ushort_t)0;
    }
  }
}

// ---------------- generic 128x128 GEMM (kv projection only) ----------
__global__ __launch_bounds__(256) void gemm_bf16(
    const ushort_t* __restrict__ A, const ushort_t* __restrict__ Bt,
    ushort_t* __restrict__ Cb,
    int K, int Astride, int Bstride, int Cstride) {
  __shared__ ushort_t As[128 * 64];
  __shared__ ushort_t Bs[128 * 64];
  const int tid = threadIdx.x;
  const int wid = tid >> 6, lane = tid & 63;
  const int wr = wid >> 1, wc = wid & 1;
  const int tileM = blockIdx.x * 128, tileN = blockIdx.y * 128;

  f32x4 acc[4][4];
#pragma unroll
  for (int m = 0; m < 4; ++m)
#pragma unroll
    for (int n = 0; n < 4; ++n) acc[m][n] = (f32x4){0.f, 0.f, 0.f, 0.f};

  const int srow = lane >> 3;
  const int scol = (lane & 7) * 8;

  for (int kt = 0; kt < K; kt += 64) {
    __syncthreads();
#pragma unroll
    for (int j = 0; j < 4; ++j) {
      int s = wid * 4 + j;
      const ushort_t* ga = A + (size_t)(tileM + s * 8 + srow) * Astride + kt + scol;
      const ushort_t* gb = Bt + (size_t)(tileN + s * 8 + srow) * Bstride + kt + scol;
      async16(ga, As + s * 512);
      async16(gb, Bs + s * 512);
    }
    __syncthreads();
#pragma unroll
    for (int kc = 0; kc < 2; ++kc) {
      bf16x8 af[4], bfr[4];
#pragma unroll
      for (int m = 0; m < 4; ++m)
        af[m] = *(const bf16x8*)&As[(wr * 64 + m * 16 + (lane & 15)) * 64 + kc * 32 + (lane >> 4) * 8];
#pragma unroll
      for (int n = 0; n < 4; ++n)
        bfr[n] = *(const bf16x8*)&Bs[(wc * 64 + n * 16 + (lane & 15)) * 64 + kc * 32 + (lane >> 4) * 8];
#pragma unroll
      for (int m = 0; m < 4; ++m)
#pragma unroll
        for (int n = 0; n < 4; ++n)
          acc[m][n] = __builtin_amdgcn_mfma_f32_16x16x32_bf16(af[m], bfr[n], acc[m][n], 0, 0, 0);
    }
  }

  const int r0 = tileM + wr * 64;
  const int c0 = tileN + wc * 64;
  const int rl2 = (lane >> 4) * 4;
  const int cl = lane & 15;
#pragma unroll
  for (int m = 0; m < 4; ++m)
#pragma unroll
    for (int n = 0; n < 4; ++n) {
      int col = c0 + n * 16 + cl;
#pragma unroll
      for (int r = 0; r < 4; ++r)
        Cb[(size_t)(r0 + m * 16 + rl2 + r) * Cstride + col] = f2bf(acc[m][n][r]);
    }
}

__global__ void vtrans_kernel(const ushort_t* __restrict__ kvb,
                              ushort_t* __restrict__ vt) {
  const int h = blockIdx.y, b = blockIdx.z;
  const int wid = threadIdx.x >> 6, lane = threadIdx.x & 63;
  const int d = blockIdx.x * 4 + wid;
  ushort_t* dst = vt + (size_t)(b * HEADS + h) * (64 * VT_STR) + d * VT_STR;
  for (int kv = lane; kv < VT_STR; kv += 64)
    dst[kv] = (kv < NKV)
        ? kvb[(size_t)(b * NKV + kv) * 1024 + 512 + h * 64 + d]
        : (ushort_t)0;
}

// ---------------- q-proj, pipelined (r5 version) ---------------------------
__global__ __launch_bounds__(512, 2) void gemm_qproj_p(
    const float* __restrict__ x, const ushort_t* __restrict__ Wt,
    ushort_t* __restrict__ qb) {
  extern __shared__ char sm[];
  const int tid = threadIdx.x, wid = tid >> 6, lane = tid & 63;
  const int rl = lane & 15, g = lane >> 4;
  const int wr = wid & 1, wc = wid >> 1;
  const size_t Mbase = (size_t)blockIdx.x * 128;

  size_t asrc[2]; unsigned adst[2];
#pragma unroll
  for (int i = 0; i < 2; ++i) {
    int c = tid + i * 512, row = c >> 3, c16 = c & 7;
    asrc[i] = (Mbase + row) * 1280 + (unsigned)((c16 * 16) ^ ((row & 7) << 4));
    adst[i] = c * 16;
  }
  size_t bsrc[4]; unsigned bdst[4];
#pragma unroll
  for (int i = 0; i < 4; ++i) {
    int c = tid + i * 512, row = c >> 2, c16 = c & 3;
    bsrc[i] = (size_t)row * 640 + (unsigned)((c16 * 16) ^ ((row & 3) << 4));
    bdst[i] = 16384 + c * 16;
  }
  const char* xB = (const char*)x;
  const char* WtB = (const char*)Wt;

  f32x4 acc[4][8];
#pragma unroll
  for (int m = 0; m < 4; ++m)
#pragma unroll
    for (int n = 0; n < 8; ++n) acc[m][n] = (f32x4){0.f, 0.f, 0.f, 0.f};

#define QSTAGE(K)                                                           \
  {                                                                         \
    char* bb = sm + (unsigned)((K) % 3) * 49152u;                           \
    _Pragma("unroll")                                                       \
    for (int i = 0; i < 2; ++i)                                             \
      async16((const ushort_t*)(xB + asrc[i] + (size_t)(K) * 128),          \
              (ushort_t*)(bb + adst[i]));                                   \
    _Pragma("unroll")                                                       \
    for (int i = 0; i < 4; ++i)                                             \
      async16((const ushort_t*)(WtB + bsrc[i] + (size_t)(K) * 64),          \
              (ushort_t*)(bb + bdst[i]));                                   \
  }

  QSTAGE(0)
  QSTAGE(1)
  for (int s = 0; s < 10; ++s) {
    if (s < 8) QSTAGE(s + 2)
    if (s < 8)       { VMCNT(12); }
    else if (s == 8) { VMCNT(6); }
    else             { VMCNT(0); }
    __builtin_amdgcn_sched_barrier(0);
    __builtin_amdgcn_s_barrier();
    __builtin_amdgcn_sched_barrier(0);

    const char* Ab = sm + (unsigned)(s % 3) * 49152u;
    const char* Bb = Ab + 16384;
    bf16x8 af[4], bfr[8];
#pragma unroll
    for (int m = 0; m < 4; ++m) {
      const int row = wr * 64 + m * 16 + rl;
      const int sw = (row & 7) << 4;
      f32x4 lo = *(const f32x4*)(Ab + row * 128 + ((g * 32) ^ sw));
      f32x4 hi = *(const f32x4*)(Ab + row * 128 + ((g * 32 + 16) ^ sw));
      af[m] = cvt8(lo, hi);
    }
#pragma unroll
    for (int n = 0; n < 8; ++n) {
      const int row = wc * 128 + n * 16 + rl;
      bfr[n] = *(const bf16x8*)(Bb + row * 64 + ((g * 16) ^ ((row & 3) << 4)));
    }
#pragma unroll
    for (int m = 0; m < 4; ++m)
#pragma unroll
      for (int n = 0; n < 8; ++n)
        acc[m][n] = __builtin_amdgcn_mfma_f32_16x16x32_bf16(af[m], bfr[n], acc[m][n], 0, 0, 0);
    __builtin_amdgcn_sched_barrier(0);
    __builtin_amdgcn_s_barrier();
    __builtin_amdgcn_sched_barrier(0);
  }

  // epilogue: acc -> LDS (bf16) -> coalesced 16B stores, 2 halves of 64 rows
  ushort_t* eb = (ushort_t*)sm;
#pragma unroll
  for (int h = 0; h < 2; ++h) {
    if (h) __syncthreads();
    if (wr == h) {
#pragma unroll
      for (int m = 0; m < 4; ++m)
#pragma unroll
        for (int n = 0; n < 8; ++n)
#pragma unroll
          for (int r = 0; r < 4; ++r)
            eb[(m * 16 + g * 4 + r) * 512 + wc * 128 + n * 16 + rl] = f2bf(acc[m][n][r]);
    }
    __syncthreads();
#pragma unroll
    for (int i = 0; i < 8; ++i) {
      int c = tid + i * 512, row = c >> 6;
      *(bf16x8*)(qb + (Mbase + h * 64 + row) * 512 + (c & 63) * 8) =
          *(const bf16x8*)(eb + c * 8);
    }
  }
}

// ---------------- out-proj, pipelined (r5 version) -------------------------
__global__ __launch_bounds__(512, 2) void gemm_oproj_p(
    const ushort_t* __restrict__ A, const ushort_t* __restrict__ Wt,
    const float* __restrict__ bo, float* __restrict__ out) {
  extern __shared__ char sm[];
  const int tid = threadIdx.x, wid = tid >> 6, lane = tid & 63;
  const int rl = lane & 15, g = lane >> 4;
  const int wr = wid & 1, wc = wid >> 1;
  const size_t Mbase = (size_t)blockIdx.x * 128;

  size_t asrc; unsigned adst;
  {
    int c = tid, row = c >> 2, c16 = c & 3;
    asrc = (Mbase + row) * 1024 + (unsigned)((c16 * 16) ^ ((row & 3) << 4));
    adst = c * 16;
  }
  size_t bsrc[3]; unsigned bdst[3];
#pragma unroll
  for (int i = 0; i < 3; ++i) {
    int c = tid + i * 512, row = c >> 2, c16 = c & 3;
    bsrc[i] = (size_t)row * 1024 + (unsigned)((c16 * 16) ^ ((row & 3) << 4));
    bdst[i] = 8192 + c * 16;
  }
  const char* AB = (const char*)A;
  const char* WtB = (const char*)Wt;

  f32x4 acc[4][6];
#pragma unroll
  for (int m = 0; m < 4; ++m)
#pragma unroll
    for (int n = 0; n < 6; ++n) acc[m][n] = (f32x4){0.f, 0.f, 0.f, 0.f};

#define OSTAGE(K)                                                           \
  {                                                                         \
    char* bb = sm + (unsigned)((K) % 3) * 32768u;                           \
    async16((const ushort_t*)(AB + asrc + (size_t)(K) * 64),                \
            (ushort_t*)(bb + adst));                                        \
    _Pragma("unroll")                                                       \
    for (int i = 0; i < 3; ++i)                                             \
      async16((const ushort_t*)(WtB + bsrc[i] + (size_t)(K) * 64),          \
              (ushort_t*)(bb + bdst[i]));                                   \
  }

  OSTAGE(0)
  OSTAGE(1)
  for (int s = 0; s < 16; ++s) {
    if (s < 14) OSTAGE(s + 2)
    if (s < 14)       { VMCNT(8); }
    else if (s == 14) { VMCNT(4); }
    else              { VMCNT(0); }
    __builtin_amdgcn_sched_barrier(0);
    __builtin_amdgcn_s_barrier();
    __builtin_amdgcn_sched_barrier(0);

    const char* Ab = sm + (unsigned)(s % 3) * 32768u;
    const char* Bb = Ab + 8192;
    bf16x8 af[4], bfr[6];
#pragma unroll
    for (int m = 0; m < 4; ++m) {
      const int row = wr * 64 + m * 16 + rl;
      af[m] = *(const bf16x8*)(Ab + row * 64 + ((g * 16) ^ ((row & 3) << 4)));
    }
#pragma unroll
    for (int n = 0; n < 6; ++n) {
      const int row = wc * 96 + n * 16 + rl;
      bfr[n] = *(const bf16x8*)(Bb + row * 64 + ((g * 16) ^ ((row & 3) << 4)));
    }
#pragma unroll
    for (int m = 0; m < 4; ++m)
#pragma unroll
      for (int n = 0; n < 6; ++n)
        acc[m][n] = __builtin_amdgcn_mfma_f32_16x16x32_bf16(af[m], bfr[n], acc[m][n], 0, 0, 0);
    __builtin_amdgcn_sched_barrier(0);
    __builtin_amdgcn_s_barrier();
    __builtin_amdgcn_sched_barrier(0);
  }

  const size_t r0 = Mbase + wr * 64;
  const int c0 = wc * 96;
#pragma unroll
  for (int n = 0; n < 6; ++n) {
    int col = c0 + n * 16 + rl;
    if (col < QDIM) {
      float bv = bo[col];
#pragma unroll
      for (int m = 0; m < 4; ++m)
#pragma unroll
        for (int r = 0; r < 4; ++r)
          out[(r0 + m * 16 + g * 4 + r) * QDIM + col] = acc[m][n][r] + bv;
    }
  }
}

// ---------------- fused attention (r2 version, unchanged) ----------------
__global__ __launch_bounds__(256) void attn_kernel(
    const ushort_t* __restrict__ qb, const ushort_t* __restrict__ kvb,
    const ushort_t* __restrict__ vt, const float* __restrict__ biasT,
    ushort_t* __restrict__ ab) {
  __shared__ ushort_t Vt[64 * VT_STR];
  __shared__ ushort_t P[4 * 16 * VT_STR];
  const int qt = blockIdx.x, h = blockIdx.y, b = blockIdx.z;
  const int tid = threadIdx.x, wid = tid >> 6, lane = tid & 63;
  const int rl = lane & 15;
  const int kh = (lane >> 4) * 8;

  const ushort_t* vtg = vt + (size_t)(b * HEADS + h) * (64 * VT_STR);
  for (int i = tid; i < 832; i += 256) async16(vtg + i * 8, Vt + i * 8);
  for (int i = tid; i < 832; i += 256)
    *(bf16x8*)&P[i * 8] = (bf16x8){0, 0, 0, 0, 0, 0, 0, 0};

  bf16x8 kf[5][2];
  float bias_v[5];
#pragma unroll
  for (int nt = 0; nt < 5; ++nt) {
    int kv = nt * 16 + rl;
    bias_v[nt] = biasT[b * 80 + kv];
    kf[nt][0] = (bf16x8){0, 0, 0, 0, 0, 0, 0, 0};
    kf[nt][1] = (bf16x8){0, 0, 0, 0, 0, 0, 0, 0};
    if (kv < NKV) {
      const ushort_t* kp = &kvb[(size_t)(b * NKV + kv) * 1024 + h * 64 + kh];
      kf[nt][0] = *(const bf16x8*)kp;
      kf[nt][1] = *(const bf16x8*)(kp + 32);
    }
  }
  __syncthreads();

  const int qbase = b * NQ + qt * 256;
  const int pbase = wid * (16 * VT_STR);
#pragma unroll 1
  for (int chunk = 0; chunk < 4; ++chunk) {
    if (chunk) __syncthreads();
    const int row0 = chunk * 64 + wid * 16;

    const ushort_t* qp = &qb[(size_t)(qbase + row0 + rl) * INNER + h * 64 + kh];
    bf16x8 qf0 = *(const bf16x8*)qp;
    bf16x8 qf1 = *(const bf16x8*)(qp + 32);

    f32x4 s[5];
#pragma unroll
    for (int nt = 0; nt < 5; ++nt) {
      s[nt] = (f32x4){0.f, 0.f, 0.f, 0.f};
      s[nt] = __builtin_amdgcn_mfma_f32_16x16x32_bf16(qf0, kf[nt][0], s[nt], 0, 0, 0);
      s[nt] = __builtin_amdgcn_mfma_f32_16x16x32_bf16(qf1, kf[nt][1], s[nt], 0, 0, 0);
    }

    float mx[4] = {-3.0e38f, -3.0e38f, -3.0e38f, -3.0e38f};
#pragma unroll
    for (int nt = 0; nt < 5; ++nt)
#pragma unroll
      for (int r = 0; r < 4; ++r) {
        float v = s[nt][r] + bias_v[nt];
        s[nt][r] = v;
        mx[r] = fmaxf(mx[r], v);
      }
#pragma unroll
    for (int d = 1; d < 16; d <<= 1)
#pragma unroll
      for (int r = 0; r < 4; ++r) mx[r] = fmaxf(mx[r], __shfl_xor(mx[r], d, 64));

    float sm_[4] = {0.f, 0.f, 0.f, 0.f};
#pragma unroll
    for (int nt = 0; nt < 5; ++nt)
#pragma unroll
      for (int r = 0; r < 4; ++r) {
        float p = __expf(s[nt][r] - mx[r]);
        s[nt][r] = p;
        sm_[r] += p;
      }
#pragma unroll
    for (int d = 1; d < 16; d <<= 1)
#pragma unroll
      for (int r = 0; r < 4; ++r) sm_[r] += __shfl_xor(sm_[r], d, 64);

    float rcp[4];
#pragma unroll
    for (int r = 0; r < 4; ++r) rcp[r] = 1.0f / sm_[r];

#pragma unroll
    for (int nt = 0; nt < 5; ++nt)
#pragma unroll
      for (int r = 0; r < 4; ++r)
        P[pbase + ((lane >> 4) * 4 + r) * VT_STR + nt * 16 + rl] = f2bf(s[nt][r]);

    f32x4 o[4];
#pragma unroll
    for (int n = 0; n < 4; ++n) o[n] = (f32x4){0.f, 0.f, 0.f, 0.f};
#pragma unroll
    for (int kc = 0; kc < 3; ++kc) {
      bf16x8 pf = *(const bf16x8*)&P[pbase + rl * VT_STR + kc * 32 + kh];
#pragma unroll
      for (int n = 0; n < 4; ++n) {
        bf16x8 vf = *(const bf16x8*)&Vt[(n * 16 + rl) * VT_STR + kc * 32 + kh];
        o[n] = __builtin_amdgcn_mfma_f32_16x16x32_bf16(pf, vf, o[n], 0, 0, 0);
      }
    }

#pragma unroll
    for (int n = 0; n < 4; ++n)
#pragma unroll
      for (int r = 0; r < 4; ++r)
        P[pbase + ((lane >> 4) * 4 + r) * VT_STR + n * 16 + rl] = f2bf(o[n][r] * rcp[r]);

    __syncthreads();

    {
      const int rflat = tid >> 2, d0 = (tid & 3) * 16;
      const ushort_t* src = &P[(rflat >> 4) * (16 * VT_STR) + (rflat & 15) * VT_STR + d0];
      ushort_t* dst = &ab[(size_t)(qbase + chunk * 64 + rflat) * INNER + h * 64 + d0];
      *(bf16x8*)dst = *(const bf16x8*)src;
      *(bf16x8*)(dst + 8) = *(const bf16x8*)(src + 8);
    }
  }
}

// ---------------- host ----------------
extern "C" void kernel_launch(void* const* d_in, const int* in_sizes, int n_in,
                              void* d_out, int out_size, void* d_ws, size_t ws_size,
                              hipStream_t stream) {
  (void)in_sizes; (void)n_in; (void)out_size; (void)ws_size;
  const float* x   = (const float*)d_in[0];
  const float* ctx = (const float*)d_in[1];
  const unsigned char* mask = (const unsigned char*)d_in[2];
  const float* Wq = (const float*)d_in[3];
  const float* Wk = (const float*)d_in[4];
  const float* Wv = (const float*)d_in[5];
  const float* Wo = (const float*)d_in[6];
  const float* bo = (const float*)d_in[7];
  float* out = (float*)d_out;

  hipFuncSetAttribute((const void*)gemm_qproj_p,
                      hipFuncAttributeMaxDynamicSharedMemorySize, 147456);
  hipFuncSetAttribute((const void*)gemm_oproj_p,
                      hipFuncAttributeMaxDynamicSharedMemorySize, 98304);

  char* ws = (char*)d_ws;
  size_t off = 0;
  auto alloc = [&](size_t bytes) {
    char* p = ws + off;
    off += (bytes + 255) & ~(size_t)255;
    return p;
  };
  float*    biasT = (float*)alloc(B_SZ * 80 * sizeof(float));
  ushort_t* ab    = (ushort_t*)alloc((size_t)M_ROWS * INNER * 2);
  ushort_t* qb    = (ushort_t*)alloc((size_t)M_ROWS * INNER * 2);
  ushort_t* cb    = (ushort_t*)alloc((size_t)1280 * CDIM * 2);
  ushort_t* Wqb   = (ushort_t*)alloc((size_t)INNER * QDIM * 2);   // (0.125*Wq)^T [512][320]
  ushort_t* Wkvb  = (ushort_t*)alloc((size_t)1024 * CDIM * 2);    // [[Wk^T];[Wv^T]]
  ushort_t* Wob   = (ushort_t*)alloc((size_t)384 * INNER * 2);    // Wo^T pad [384][512]
  ushort_t* kvb   = (ushort_t*)alloc((size_t)1280 * 1024 * 2);
  ushort_t* vt    = (ushort_t*)alloc((size_t)B_SZ * HEADS * 64 * VT_STR * 2);

  mask_bias_kernel<<<1, 256, 0, stream>>>(mask, biasT);
  prep_kernel<<<2048, 256, 0, stream>>>(ctx, cb, Wq, Wqb, Wk, Wv, Wkvb, Wo, Wob);

  // q = bf16(x) @ (0.125*Wq) — pipelined, x read exactly once
  gemm_qproj_p<<<M_ROWS / 128, 512, 147456, stream>>>(x, Wqb, qb);
  // [k|v] = ctx @ [Wk|Wv]
  dim3 g2(1280 / 128, 1024 / 128);
  gemm_bf16<<<g2, 256, 0, stream>>>(cb, Wkvb, kvb, CDIM, CDIM, CDIM, 1024);
  // V -> vt[b][h][d][104]
  vtrans_kernel<<<dim3(16, HEADS, B_SZ), 256, 0, stream>>>(kvb, vt);
  // attention
  attn_kernel<<<dim3(NQ / 256, HEADS, B_SZ), 256, 0, stream>>>(qb, kvb, vt, biasT, ab);
  // out = ab @ Wo + bo — pipelined
  gemm_oproj_p<<<M_ROWS / 128, 512, 98304, stream>>>(ab, Wob, bo, out);
}